// Round 4
// baseline (31713.419 us; speedup 1.0000x reference)
//
#include <hip/hip_runtime.h>

// LSTM 2-layer fused persistent kernel, full fp32.
// 256 workgroups (1 per batch row / CU), 1024 threads: thread = (row g of
// 4H=512, half of K). Per-thread live weights <= 16 float4 (64 VGPR).
//
// VGPR history: (512,2)->128 VGPR; (1024,4)->64+spill; (1024,1)->STILL 64+
// spill. Conclusion: launch_bounds only sets MIN waves/EU; the backend's
// occupancy TARGET for 1024-thread groups defaults to 8 waves/EU -> 64-VGPR
// budget -> spill. amdgpu_waves_per_eu(4,4) pins target = 4 waves/EU ->
// budget 512/4 = 128 VGPR. LDS (93KB) already caps at 1 block/CU = 4
// waves/EU, so occupancy is unaffected.
// KEEP4 empty-asm pins loaded weights (anti-remat, R1's 30GB refetch).
// Per chunk of TC=32 steps:
//   A: stage x chunk to LDS (+carry h0)
//   B: xp0[t][g] = bias0 + Wih0[g,:].x_t     (batched mini-GEMM, K=64)
//   C: layer0 serial: gates = xp0 + Whh0.h0  (16 ds_read_b128 + 64 FMA/thr)
//   D: xp1[t][g] = bias1 + Wih1[g,:].h0_t    (batched mini-GEMM, K=128)
//   E: layer1 serial: gates = xp1 + Whh1.h1

#define NB   256
#define TSEQ 1024
#define II   64
#define HH   128
#define G4   512
#define TC   32
#define NCH  (TSEQ/TC)

#define KEEP4(v) asm volatile("" : "+v"((v).x), "+v"((v).y), "+v"((v).z), "+v"((v).w))

__device__ __forceinline__ float sigm(float x){ return 1.f/(1.f+__expf(-x)); }
__device__ __forceinline__ float tanh_f(float x){
    float ax = fabsf(x);
    float e  = __expf(2.f*ax);
    float t  = 1.f - 2.f/(e + 1.f);
    return copysignf(t, x);
}

__global__ __launch_bounds__(1024)
__attribute__((amdgpu_waves_per_eu(4, 4)))
void lstm_all(const float* __restrict__ x,
              const float* __restrict__ Wih0, const float* __restrict__ Whh0,
              const float* __restrict__ bih0, const float* __restrict__ bhh0,
              const float* __restrict__ Wih1, const float* __restrict__ Whh1,
              const float* __restrict__ bih1, const float* __restrict__ bhh1,
              const float* __restrict__ Wlin, const float* __restrict__ blin,
              float* __restrict__ out)
{
    const int b    = blockIdx.x;
    const int tid  = threadIdx.x;
    const int row  = tid >> 1;    // gate row 0..511
    const int half = tid & 1;     // K-half

    __shared__ __align__(16) float xp[TC][G4];        // 65,536 B (xp0 then xp1)
    __shared__ __align__(16) float h0buf[TC+1][HH];   // 16,896 B
    __shared__ __align__(16) float xc[TC][II];        //  8,192 B
    __shared__ __align__(16) float gates[G4];         //  2,048 B
    __shared__ __align__(16) float h1buf[HH];         //    512 B
    // total ~93 KB -> 1 block/CU

    float c0 = 0.f, c1 = 0.f;     // cell state, owned by tid<128
    const float bias0 = bih0[row] + bhh0[row];
    const float bias1 = bih1[row] + bhh1[row];
    const bool  tanh_gate = (row >= 2*HH) && (row < 3*HH);  // wave-uniform

    if (tid < HH) { h0buf[0][tid] = 0.f; h1buf[tid] = 0.f; }

    const float* xb = x + (size_t)b * TSEQ * II;

    for (int ch = 0; ch < NCH; ++ch) {
        // ---------- Phase A: stage x chunk, carry h0 ----------
        if (tid < 512) {
            ((float4*)&xc[0][0])[tid] =
                ((const float4*)(xb + (size_t)ch * TC * II))[tid];
        }
        if (ch > 0 && tid < HH) h0buf[0][tid] = h0buf[TC][tid];
        __syncthreads();

        // ---------- Phase B: xp0 = bias0 + Wih0 . x  (K half = 32) ----------
        {
            float4 w[8];
            const float4* wp = (const float4*)(Wih0 + (size_t)row*II + half*(II/2));
            #pragma unroll
            for (int i = 0; i < 8; ++i) w[i] = wp[i];
            #pragma unroll
            for (int i = 0; i < 8; ++i) KEEP4(w[i]);
            #pragma unroll
            for (int sub = 0; sub < TC/8; ++sub) {
                float acc[8];
                #pragma unroll
                for (int i = 0; i < 8; ++i) acc[i] = 0.f;
                #pragma unroll
                for (int k4 = 0; k4 < 8; ++k4) {
                    #pragma unroll
                    for (int tt = 0; tt < 8; ++tt) {
                        float4 v = *(const float4*)&xc[sub*8+tt][half*(II/2) + k4*4];
                        acc[tt] += w[k4].x*v.x + w[k4].y*v.y + w[k4].z*v.z + w[k4].w*v.w;
                    }
                }
                #pragma unroll
                for (int tt = 0; tt < 8; ++tt) {
                    float s = acc[tt] + __shfl_xor(acc[tt], 1);
                    if (half == 0) xp[sub*8+tt][row] = s + bias0;
                }
            }
        }
        __syncthreads();

        // ---------- Phase C: layer0 serial (K half = 64) ----------
        {
            float4 wh[16];
            const float4* wp = (const float4*)(Whh0 + (size_t)row*HH + half*(HH/2));
            #pragma unroll
            for (int i = 0; i < 16; ++i) wh[i] = wp[i];
            #pragma unroll
            for (int i = 0; i < 16; ++i) KEEP4(wh[i]);
            #pragma unroll 1
            for (int t = 0; t < TC; ++t) {
                float a0=0.f, a1=0.f, a2=0.f, a3=0.f;
                #pragma unroll
                for (int k4 = 0; k4 < 16; ++k4) {
                    float4 v = *(const float4*)&h0buf[t][half*(HH/2) + k4*4];
                    a0 += wh[k4].x*v.x; a1 += wh[k4].y*v.y;
                    a2 += wh[k4].z*v.z; a3 += wh[k4].w*v.w;
                }
                float s = (a0+a1)+(a2+a3);
                s += __shfl_xor(s, 1);
                if (half == 0) {
                    float pre = xp[t][row] + s;
                    gates[row] = tanh_gate ? tanh_f(pre) : sigm(pre);
                }
                __syncthreads();
                if (tid < HH) {
                    float iv = gates[tid],        fv = gates[HH + tid];
                    float gv = gates[2*HH + tid], ov = gates[3*HH + tid];
                    c0 = fv*c0 + iv*gv;
                    h0buf[t+1][tid] = ov * tanh_f(c0);
                }
                __syncthreads();
            }
        }

        // ---------- Phase D: xp1 = bias1 + Wih1 . h0  (K half = 64) ----------
        {
            float4 w[16];
            const float4* wp = (const float4*)(Wih1 + (size_t)row*HH + half*(HH/2));
            #pragma unroll
            for (int i = 0; i < 16; ++i) w[i] = wp[i];
            #pragma unroll
            for (int i = 0; i < 16; ++i) KEEP4(w[i]);
            #pragma unroll
            for (int sub = 0; sub < TC/8; ++sub) {
                float acc[8];
                #pragma unroll
                for (int i = 0; i < 8; ++i) acc[i] = 0.f;
                #pragma unroll
                for (int k4 = 0; k4 < 16; ++k4) {
                    #pragma unroll
                    for (int tt = 0; tt < 8; ++tt) {
                        float4 v = *(const float4*)&h0buf[sub*8+tt+1][half*(HH/2) + k4*4];
                        acc[tt] += w[k4].x*v.x + w[k4].y*v.y + w[k4].z*v.z + w[k4].w*v.w;
                    }
                }
                #pragma unroll
                for (int tt = 0; tt < 8; ++tt) {
                    float s = acc[tt] + __shfl_xor(acc[tt], 1);
                    if (half == 0) xp[sub*8+tt][row] = s + bias1;
                }
            }
        }
        __syncthreads();

        // ---------- Phase E: layer1 serial (K half = 64) ----------
        {
            float4 wh[16];
            const float4* wp = (const float4*)(Whh1 + (size_t)row*HH + half*(HH/2));
            #pragma unroll
            for (int i = 0; i < 16; ++i) wh[i] = wp[i];
            #pragma unroll
            for (int i = 0; i < 16; ++i) KEEP4(wh[i]);
            #pragma unroll 1
            for (int t = 0; t < TC; ++t) {
                float a0=0.f, a1=0.f, a2=0.f, a3=0.f;
                #pragma unroll
                for (int k4 = 0; k4 < 16; ++k4) {
                    float4 v = *(const float4*)&h1buf[half*(HH/2) + k4*4];
                    a0 += wh[k4].x*v.x; a1 += wh[k4].y*v.y;
                    a2 += wh[k4].z*v.z; a3 += wh[k4].w*v.w;
                }
                float s = (a0+a1)+(a2+a3);
                s += __shfl_xor(s, 1);
                if (half == 0) {
                    float pre = xp[t][row] + s;
                    gates[row] = tanh_gate ? tanh_f(pre) : sigm(pre);
                }
                __syncthreads();
                if (tid < HH) {
                    float iv = gates[tid],        fv = gates[HH + tid];
                    float gv = gates[2*HH + tid], ov = gates[3*HH + tid];
                    c1 = fv*c1 + iv*gv;
                    h1buf[tid] = ov * tanh_f(c1);
                }
                __syncthreads();
            }
        }
    }

    // ---------- final linear: out[b] = h1 . Wlin[0,:] + blin ----------
    if (tid < 64) {
        float s = h1buf[tid]*Wlin[tid] + h1buf[tid+64]*Wlin[tid+64];
        #pragma unroll
        for (int off = 32; off; off >>= 1) s += __shfl_down(s, off);
        if (tid == 0) out[b] = s + blin[0];
    }
}

extern "C" void kernel_launch(void* const* d_in, const int* in_sizes, int n_in,
                              void* d_out, int out_size, void* d_ws, size_t ws_size,
                              hipStream_t stream)
{
    const float* x    = (const float*)d_in[0];
    const float* Wih0 = (const float*)d_in[1];
    const float* Whh0 = (const float*)d_in[2];
    const float* bih0 = (const float*)d_in[3];
    const float* bhh0 = (const float*)d_in[4];
    const float* Wih1 = (const float*)d_in[5];
    const float* Whh1 = (const float*)d_in[6];
    const float* bih1 = (const float*)d_in[7];
    const float* bhh1 = (const float*)d_in[8];
    const float* Wlin = (const float*)d_in[9];
    const float* blin = (const float*)d_in[10];
    float* out = (float*)d_out;

    hipLaunchKernelGGL(lstm_all, dim3(NB), dim3(1024), 0, stream,
                       x, Wih0, Whh0, bih0, bhh0,
                       Wih1, Whh1, bih1, bhh1, Wlin, blin, out);
}

// Round 5
// 5717.461 us; speedup vs baseline: 5.5468x; 5.5468x over previous
//
#include <hip/hip_runtime.h>

// LSTM 2-layer fused persistent kernel, full fp32.
// 256 blocks (1 per batch row / CU) x 512 threads; thread tid owns gate row
// gr = (tid&3)*128 + (tid>>2)  (gate g=tid&3 in {i,f,g,o}, unit j=tid>>2).
// Proven-VGPR regime: (512,2) -> 128-VGPR grant (R1). Per-thread live
// weights capped at 20 float4 (80 VGPR): Whh cols [0,80) in registers,
// cols [80,128) in a transposed LDS tile Wldst[12][512] (float4, lane-
// consecutive reads = conflict-free), restaged from L2 per chunk-phase.
// Whh CANNOT be fully reg-resident (needs 128 fl/thr ~ 165 VGPR, grant 128)
// nor fully LDS-resident (256KB > 160KB) -- hybrid is forced.
// Chunk TC=16 steps: A(stage x, carry h0, Wldst<-Whh0) / B(xp0 mini-GEMM) /
// C(layer0 serial) / stage Wldst<-Whh1 / D(xp1 mini-GEMM, 2-pass K) /
// E(layer1 serial).  Activations: sigm(x)=0.5*(1+tanh(x/2)) -> uniform
// tanh-based code, no lane divergence from the row permutation.

#define NB   256
#define TSEQ 1024
#define II   64
#define HH   128
#define G4   512
#define TC   16
#define NCH  (TSEQ/TC)
#define KREG 80            // Whh cols in registers (20 float4)
#define KLDS 12            // remaining cols as float4 count (48 cols)

#define KEEP4(v) asm volatile("" : "+v"((v).x), "+v"((v).y), "+v"((v).z), "+v"((v).w))

__device__ __forceinline__ float tanh_f(float x){
    float ax = fabsf(x);
    float e  = __expf(2.f*ax);
    float t  = 1.f - 2.f/(e + 1.f);
    return copysignf(t, x);
}

__global__ __launch_bounds__(512, 2)
void lstm_all(const float* __restrict__ x,
              const float* __restrict__ Wih0, const float* __restrict__ Whh0,
              const float* __restrict__ bih0, const float* __restrict__ bhh0,
              const float* __restrict__ Wih1, const float* __restrict__ Whh1,
              const float* __restrict__ bih1, const float* __restrict__ bhh1,
              const float* __restrict__ Wlin, const float* __restrict__ blin,
              float* __restrict__ out)
{
    const int b   = blockIdx.x;
    const int tid = threadIdx.x;
    const int g   = tid & 3;          // gate: 0=i 1=f 2=g 3=o
    const int gr  = g * HH + (tid >> 2);  // row in weight matrices

    __shared__ __align__(16) float  xp[TC][G4];        // 32 KB
    __shared__ __align__(16) float4 Wldst[KLDS][G4];   // 96 KB (cols 80..128)
    __shared__ __align__(16) float  h0buf[TC+1][HH];   // 8.7 KB
    __shared__ __align__(16) float  xc[TC][II];        // 4 KB
    __shared__ __align__(16) float  gates[G4];         // 2 KB
    __shared__ __align__(16) float  h1buf[HH];         // 0.5 KB
    // total ~143 KB -> 1 block/CU

    float c0 = 0.f, c1 = 0.f;         // cell state (threads tid<128: unit j=tid)
    const bool is_g = (g == 2);

    if (tid < HH) { h0buf[0][tid] = 0.f; h1buf[tid] = 0.f; }

    const float* xb = x + (size_t)b * TSEQ * II;

    for (int ch = 0; ch < NCH; ++ch) {
        // ---------- A: stage Wldst<-Whh0, x chunk, carry h0 ----------
        {
            const float* wsrc = Whh0 + (size_t)gr * HH + KREG;
            #pragma unroll
            for (int j = 0; j < KLDS; ++j)
                Wldst[j][tid] = *(const float4*)(wsrc + 4*j);
        }
        if (tid < 256) {
            ((float4*)&xc[0][0])[tid] =
                ((const float4*)(xb + (size_t)ch * TC * II))[tid];
        }
        if (ch > 0 && tid < HH) h0buf[0][tid] = h0buf[TC][tid];
        __syncthreads();

        // ---------- B: xp0[t][tid] = bias0 + Wih0[gr,:].x_t ----------
        {
            float4 w[II/4];
            const float4* wp = (const float4*)(Wih0 + (size_t)gr * II);
            #pragma unroll
            for (int i = 0; i < II/4; ++i) w[i] = wp[i];
            #pragma unroll
            for (int i = 0; i < II/4; ++i) KEEP4(w[i]);
            const float bias0 = bih0[gr] + bhh0[gr];
            #pragma unroll 1
            for (int t = 0; t < TC; ++t) {
                float a0=0.f, a1=0.f, a2=0.f, a3=0.f;
                const float4* xv = (const float4*)&xc[t][0];
                #pragma unroll
                for (int i = 0; i < II/4; ++i) {
                    float4 v = xv[i];
                    a0 += w[i].x*v.x; a1 += w[i].y*v.y;
                    a2 += w[i].z*v.z; a3 += w[i].w*v.w;
                }
                xp[t][tid] = bias0 + ((a0+a1)+(a2+a3));
            }
        }
        __syncthreads();

        // ---------- C: layer0 serial ----------
        {
            float4 w[KREG/4];
            const float4* wp = (const float4*)(Whh0 + (size_t)gr * HH);
            #pragma unroll
            for (int i = 0; i < KREG/4; ++i) w[i] = wp[i];
            #pragma unroll
            for (int i = 0; i < KREG/4; ++i) KEEP4(w[i]);
            #pragma unroll 1
            for (int t = 0; t < TC; ++t) {
                float a0=0.f, a1=0.f, a2=0.f, a3=0.f;
                const float4* hv = (const float4*)&h0buf[t][0];
                #pragma unroll
                for (int i = 0; i < KREG/4; ++i) {
                    float4 v = hv[i];
                    a0 += w[i].x*v.x; a1 += w[i].y*v.y;
                    a2 += w[i].z*v.z; a3 += w[i].w*v.w;
                }
                #pragma unroll
                for (int j = 0; j < KLDS; ++j) {
                    float4 v = hv[KREG/4 + j];
                    float4 u = Wldst[j][tid];
                    a0 += u.x*v.x; a1 += u.y*v.y;
                    a2 += u.z*v.z; a3 += u.w*v.w;
                }
                float pre = xp[t][tid] + ((a0+a1)+(a2+a3));
                float arg = is_g ? pre : 0.5f*pre;
                float y   = tanh_f(arg);
                gates[tid] = is_g ? y : 0.5f*y + 0.5f;   // sigm via tanh
                __syncthreads();
                if (tid < HH) {
                    float4 q = *(const float4*)&gates[4*tid]; // (i,f,g,o)
                    c0 = q.y*c0 + q.x*q.z;
                    h0buf[t+1][tid] = q.w * tanh_f(c0);
                }
                __syncthreads();
            }
        }

        // ---------- stage Wldst <- Whh1 cols [80,128) ----------
        {
            const float* wsrc = Whh1 + (size_t)gr * HH + KREG;
            #pragma unroll
            for (int j = 0; j < KLDS; ++j)
                Wldst[j][tid] = *(const float4*)(wsrc + 4*j);
        }
        __syncthreads();

        // ---------- D: xp1[t][tid] = bias1 + Wih1[gr,:].h0_t (2-pass K) ----------
        #pragma unroll 1
        for (int pass = 0; pass < 2; ++pass) {
            float4 w[16];
            const float4* wp = (const float4*)(Wih1 + (size_t)gr * HH + pass*64);
            #pragma unroll
            for (int i = 0; i < 16; ++i) w[i] = wp[i];
            #pragma unroll
            for (int i = 0; i < 16; ++i) KEEP4(w[i]);
            const float bias1 = (pass == 0) ? (bih1[gr] + bhh1[gr]) : 0.f;
            #pragma unroll 1
            for (int t = 0; t < TC; ++t) {
                float a0=0.f, a1=0.f, a2=0.f, a3=0.f;
                const float4* hv = (const float4*)&h0buf[t+1][pass*64];
                #pragma unroll
                for (int i = 0; i < 16; ++i) {
                    float4 v = hv[i];
                    a0 += w[i].x*v.x; a1 += w[i].y*v.y;
                    a2 += w[i].z*v.z; a3 += w[i].w*v.w;
                }
                float s = (a0+a1)+(a2+a3);
                if (pass == 0) xp[t][tid] = bias1 + s;
                else           xp[t][tid] += s;
            }
        }
        __syncthreads();

        // ---------- E: layer1 serial ----------
        {
            float4 w[KREG/4];
            const float4* wp = (const float4*)(Whh1 + (size_t)gr * HH);
            #pragma unroll
            for (int i = 0; i < KREG/4; ++i) w[i] = wp[i];
            #pragma unroll
            for (int i = 0; i < KREG/4; ++i) KEEP4(w[i]);
            #pragma unroll 1
            for (int t = 0; t < TC; ++t) {
                float a0=0.f, a1=0.f, a2=0.f, a3=0.f;
                const float4* hv = (const float4*)&h1buf[0];
                #pragma unroll
                for (int i = 0; i < KREG/4; ++i) {
                    float4 v = hv[i];
                    a0 += w[i].x*v.x; a1 += w[i].y*v.y;
                    a2 += w[i].z*v.z; a3 += w[i].w*v.w;
                }
                #pragma unroll
                for (int j = 0; j < KLDS; ++j) {
                    float4 v = hv[KREG/4 + j];
                    float4 u = Wldst[j][tid];
                    a0 += u.x*v.x; a1 += u.y*v.y;
                    a2 += u.z*v.z; a3 += u.w*v.w;
                }
                float pre = xp[t][tid] + ((a0+a1)+(a2+a3));
                float arg = is_g ? pre : 0.5f*pre;
                float y   = tanh_f(arg);
                gates[tid] = is_g ? y : 0.5f*y + 0.5f;
                __syncthreads();
                if (tid < HH) {
                    float4 q = *(const float4*)&gates[4*tid];
                    c1 = q.y*c1 + q.x*q.z;
                    h1buf[tid] = q.w * tanh_f(c1);
                }
                __syncthreads();
            }
        }
    }

    // ---------- final linear: out[b] = h1 . Wlin[0,:] + blin ----------
    if (tid < 64) {
        float s = h1buf[tid]*Wlin[tid] + h1buf[tid+64]*Wlin[tid+64];
        #pragma unroll
        for (int off = 32; off; off >>= 1) s += __shfl_down(s, off);
        if (tid == 0) out[b] = s + blin[0];
    }
}

extern "C" void kernel_launch(void* const* d_in, const int* in_sizes, int n_in,
                              void* d_out, int out_size, void* d_ws, size_t ws_size,
                              hipStream_t stream)
{
    const float* x    = (const float*)d_in[0];
    const float* Wih0 = (const float*)d_in[1];
    const float* Whh0 = (const float*)d_in[2];
    const float* bih0 = (const float*)d_in[3];
    const float* bhh0 = (const float*)d_in[4];
    const float* Wih1 = (const float*)d_in[5];
    const float* Whh1 = (const float*)d_in[6];
    const float* bih1 = (const float*)d_in[7];
    const float* bhh1 = (const float*)d_in[8];
    const float* Wlin = (const float*)d_in[9];
    const float* blin = (const float*)d_in[10];
    float* out = (float*)d_out;

    hipLaunchKernelGGL(lstm_all, dim3(NB), dim3(512), 0, stream,
                       x, Wih0, Whh0, bih0, bhh0,
                       Wih1, Whh1, bih1, bhh1, Wlin, blin, out);
}